// Round 5
// baseline (670.138 us; speedup 1.0000x reference)
//
#include <hip/hip_runtime.h>

// Problem constants: B=1024, T=200, D=128, H=128
#define T_SZ 200
#define H_SZ 128

typedef __attribute__((ext_vector_type(8))) short    bf16x8;
typedef __attribute__((ext_vector_type(4))) float    f32x4;
typedef __attribute__((ext_vector_type(4))) int      i32x4;

__device__ __forceinline__ unsigned short f2bf(float f) {  // weight init only
  unsigned u = __builtin_bit_cast(unsigned, f);
  u += 0x7fffu + ((u >> 16) & 1u);
  return (unsigned short)(u >> 16);
}
// Single-instruction packed f32->bf16 (RNE, same rounding as f2bf).
__device__ __forceinline__ unsigned cvt_pk_bf16(float a, float b) {
  unsigned r;
  asm("v_cvt_pk_bf16_f32 %0, %1, %2" : "=v"(r) : "v"(a), "v"(b));
  return r;
}
__device__ __forceinline__ float sigmoid_fast(float x) {
  float e = __builtin_amdgcn_exp2f(-1.442695041f * x);
  return __builtin_amdgcn_rcpf(1.0f + e);
}
__device__ __forceinline__ float tanh_fast(float x) {
  float e = __builtin_amdgcn_exp2f(2.885390082f * x);
  return 1.0f - 2.0f * __builtin_amdgcn_rcpf(e + 1.0f);
}
// lgkmcnt(0)-only barrier: does NOT drain vmcnt (global stores / register
// prefetch loads stay in flight). 0xc07f = vmcnt(63) expcnt(7) lgkmcnt(0).
__device__ __forceinline__ void ldsbar() {
  __asm__ __volatile__("" ::: "memory");
  __builtin_amdgcn_s_waitcnt(0xc07f);
  __builtin_amdgcn_s_barrier();
  __asm__ __volatile__("" ::: "memory");
}

// ---------------------------------------------------------------------------
// Fused GRU. Wave w owns gate cols [16w,+16) (r) and [128+16w,+16) (u), and
// h/cand col colc = 16w+m16 — C-layout == h register layout, so r*h, u, and
// the h update are pure register ops.
// LDS carries ONLY the two structurally-required exchanges (hA, rhA).
// x never touches LDS: every wave's x A-fragment is loaded directly from
// global (per-lane dwordx4, one-step prefetch => full-step latency margin;
// the wg's 8KB x-tile is L2-resident so the 8x wave redundancy is L2 hits).
// Phase structure:
//   P1(t): haf read -> r-MFMA(2+2, C-init = x-proj) -> sigmoid -> rh publish.
//   P2(t): rhf read; u-MFMA(4-chain, reg-only) + x(t+1) cvt + xproj(t+1)
//          (12 MFMA) fill the read shadow; cand-MFMA(2+2); activations;
//          h publish; issue x(t+2) loads.
// ---------------------------------------------------------------------------
__global__ __launch_bounds__(512, 1) void gru_fused(
    const float* __restrict__ X,    // [B,T,D]
    const int*   __restrict__ seq_len,
    const float* __restrict__ Wg,   // [256,256] rows 0..127 x-part, 128.. h-part
    const float* __restrict__ bg,   // [256]
    const float* __restrict__ Wc,   // [256,128] rows 0..127 x-part, 128.. rh-part
    const float* __restrict__ bc,   // [128]
    float* __restrict__ Y)          // [B,T,H]
{
  __shared__ unsigned short hA[16 * 136];      // h bf16, A-layout [row][k]
  __shared__ unsigned short rhA[16 * 136];     // r*h bf16, A-layout

  const int tid  = threadIdx.x;
  const int lane = tid & 63;
  const int w    = tid >> 6;   // 0..7
  const int m16  = lane & 15;
  const int q    = lane >> 4;

  // ---- weight B-fragments (kb 0..3 = x-part rows 0..127, 4..7 = h-part) ----
  // nt=0: r cols 16w..16w+16; nt=1: u cols 128+16w..+16.
  bf16x8 wgf[2][8];
  float  gbias[2];
  #pragma unroll
  for (int nt = 0; nt < 2; ++nt) {
    int col = nt * 128 + w * 16 + m16;
    gbias[nt] = bg[col];
    #pragma unroll
    for (int kb = 0; kb < 8; ++kb) {
      bf16x8 f;
      #pragma unroll
      for (int j = 0; j < 8; ++j)
        f[j] = (short)f2bf(Wg[(size_t)(kb * 32 + q * 8 + j) * 256 + col]);
      wgf[nt][kb] = f;
    }
  }
  const int colc = w * 16 + m16;  // this wave's cand/h column
  bf16x8 wcf[8];
  float  cbias = bc[colc];
  #pragma unroll
  for (int kb = 0; kb < 8; ++kb) {
    bf16x8 f;
    #pragma unroll
    for (int j = 0; j < 8; ++j)
      f[j] = (short)f2bf(Wc[(size_t)(kb * 32 + q * 8 + j) * 128 + colc]);
    wcf[kb] = f;
  }

  const int bt = blockIdx.x;  // 0..63
  int slen[4];
  #pragma unroll
  for (int i = 0; i < 4; ++i) slen[i] = seq_len[bt * 16 + q * 4 + i];

  float h[4] = {0.f, 0.f, 0.f, 0.f};

  for (int idx = tid; idx < 16 * 136; idx += 512) hA[idx] = 0;

  // ---- direct global x A-fragment loads: lane (m16,q) owns row bt*16+m16,
  // k = kb*32 + q*8 + j. 8 x dwordx4 per step. ----
  const float* const xrow = X + (size_t)(bt * 16 + m16) * T_SZ * 128 + q * 8;
  f32x4 xf[8];  // prefetched x(t_next) fragment, fp32
  auto xissue = [&](int t) {
    const float* p = xrow + (size_t)t * 128;
    #pragma unroll
    for (int kb = 0; kb < 4; ++kb) {
      xf[2 * kb]     = *(const f32x4*)(p + kb * 32);
      xf[2 * kb + 1] = *(const f32x4*)(p + kb * 32 + 4);
    }
  };

  // Pipeline regs: x-projection of step t (bias folded), produced at P2(t-1).
  f32x4 axr, axu, cc;

  // xproj from the current xf contents (consumes xf; compiler inserts vmcnt).
  auto xproj = [&]() {
    bf16x8 xbf[4];
    #pragma unroll
    for (int kb = 0; kb < 4; ++kb) {
      i32x4 pk = { (int)cvt_pk_bf16(xf[2 * kb].x,     xf[2 * kb].y),
                   (int)cvt_pk_bf16(xf[2 * kb].z,     xf[2 * kb].w),
                   (int)cvt_pk_bf16(xf[2 * kb + 1].x, xf[2 * kb + 1].y),
                   (int)cvt_pk_bf16(xf[2 * kb + 1].z, xf[2 * kb + 1].w) };
      xbf[kb] = __builtin_bit_cast(bf16x8, pk);
    }
    f32x4 c_ = { cbias, cbias, cbias, cbias };
    f32x4 r_ = { gbias[0], gbias[0], gbias[0], gbias[0] };
    f32x4 u_ = { gbias[1], gbias[1], gbias[1], gbias[1] };
    #pragma unroll
    for (int kb = 0; kb < 4; ++kb) {
      c_ = __builtin_amdgcn_mfma_f32_16x16x32_bf16(xbf[kb], wcf[kb],    c_, 0, 0, 0);
      r_ = __builtin_amdgcn_mfma_f32_16x16x32_bf16(xbf[kb], wgf[0][kb], r_, 0, 0, 0);
      u_ = __builtin_amdgcn_mfma_f32_16x16x32_bf16(xbf[kb], wgf[1][kb], u_, 0, 0, 0);
    }
    cc = c_; axr = r_; axu = u_;
  };

  // Prologue: x(0) -> xproj(0); issue x(1); hA-zero barrier.
  xissue(0);
  ldsbar();          // hA zero-init visible (lgkm only; loads unaffected)
  {
    // consume x(0)
    bf16x8 dummy_guard;  (void)dummy_guard;
  }
  xproj();           // waits on x(0) loads
  xissue(1);

  float* const ybase = Y + (size_t)(bt * 16 + q * 4) * T_SZ * H_SZ + colc;

  for (int t = 0; t < 200; ++t) {
    // ---- P1: r gate + rh publish ONLY (minimal pre-barrier path) ----
    bf16x8 haf[4];
    #pragma unroll
    for (int kb = 0; kb < 4; ++kb)
      haf[kb] = __builtin_bit_cast(bf16x8, *(const i32x4*)&hA[m16 * 136 + kb * 32 + q * 8]);

    // r: two 2-deep MFMA chains, C-init carries bias + x-projection
    f32x4 ra = axr, rb = { 0.f, 0.f, 0.f, 0.f };
    ra = __builtin_amdgcn_mfma_f32_16x16x32_bf16(haf[0], wgf[0][4], ra, 0, 0, 0);
    ra = __builtin_amdgcn_mfma_f32_16x16x32_bf16(haf[1], wgf[0][5], ra, 0, 0, 0);
    rb = __builtin_amdgcn_mfma_f32_16x16x32_bf16(haf[2], wgf[0][6], rb, 0, 0, 0);
    rb = __builtin_amdgcn_mfma_f32_16x16x32_bf16(haf[3], wgf[0][7], rb, 0, 0, 0);

    // rh = sigmoid(r) * h — pure register op (C-layout == h layout)
    float rh0 = sigmoid_fast(ra[0] + rb[0]) * h[0];
    float rh1 = sigmoid_fast(ra[1] + rb[1]) * h[1];
    float rh2 = sigmoid_fast(ra[2] + rb[2]) * h[2];
    float rh3 = sigmoid_fast(ra[3] + rb[3]) * h[3];
    unsigned rp01 = cvt_pk_bf16(rh0, rh1);
    unsigned rp23 = cvt_pk_bf16(rh2, rh3);
    rhA[(q * 4 + 0) * 136 + colc] = (unsigned short)(rp01 & 0xffffu);
    rhA[(q * 4 + 1) * 136 + colc] = (unsigned short)(rp01 >> 16);
    rhA[(q * 4 + 2) * 136 + colc] = (unsigned short)(rp23 & 0xffffu);
    rhA[(q * 4 + 3) * 136 + colc] = (unsigned short)(rp23 >> 16);
    ldsbar();

    // ---- P2: u + candidate + xproj(t+1) + h update ----
    bf16x8 rhf[4];
    #pragma unroll
    for (int kb = 0; kb < 4; ++kb)
      rhf[kb] = __builtin_bit_cast(bf16x8, *(const i32x4*)&rhA[m16 * 136 + kb * 32 + q * 8]);

    // u: 4-deep chain, inputs all in registers — fills the rhf-read shadow.
    f32x4 ua = axu;
    ua = __builtin_amdgcn_mfma_f32_16x16x32_bf16(haf[0], wgf[1][4], ua, 0, 0, 0);
    ua = __builtin_amdgcn_mfma_f32_16x16x32_bf16(haf[1], wgf[1][5], ua, 0, 0, 0);
    ua = __builtin_amdgcn_mfma_f32_16x16x32_bf16(haf[2], wgf[1][6], ua, 0, 0, 0);
    ua = __builtin_amdgcn_mfma_f32_16x16x32_bf16(haf[3], wgf[1][7], ua, 0, 0, 0);

    // cand: 2+2 chains, C-init carries bias + x-projection (read before
    // xproj() overwrites cc — sequential semantics enforce the order).
    f32x4 ca = cc, cb = { 0.f, 0.f, 0.f, 0.f };
    ca = __builtin_amdgcn_mfma_f32_16x16x32_bf16(rhf[0], wcf[4], ca, 0, 0, 0);
    ca = __builtin_amdgcn_mfma_f32_16x16x32_bf16(rhf[1], wcf[5], ca, 0, 0, 0);
    cb = __builtin_amdgcn_mfma_f32_16x16x32_bf16(rhf[2], wcf[6], cb, 0, 0, 0);
    cb = __builtin_amdgcn_mfma_f32_16x16x32_bf16(rhf[3], wcf[7], cb, 0, 0, 0);

    if (t < 199) {
      xproj();              // x(t+1) cvt + 12 h-independent MFMAs (shadow)
      if (t < 198) xissue(t + 2);  // re-issue loads into xf (full-step margin)
    }

    f32x4 uv;
    #pragma unroll
    for (int i = 0; i < 4; ++i) uv[i] = sigmoid_fast(ua[i]);

    #pragma unroll
    for (int i = 0; i < 4; ++i) {
      float c  = tanh_fast(ca[i] + cb[i]);
      float hn = uv[i] * (h[i] - c) + c;   // u*h + (1-u)*c
      bool valid = (t < slen[i]);
      float hvz = valid ? hn : h[i];
      h[i] = hvz;
      ybase[(size_t)i * T_SZ * H_SZ + (size_t)t * H_SZ] = valid ? hn : 0.0f;
    }
    unsigned hp01 = cvt_pk_bf16(h[0], h[1]);
    unsigned hp23 = cvt_pk_bf16(h[2], h[3]);
    hA[(q * 4 + 0) * 136 + colc] = (unsigned short)(hp01 & 0xffffu);
    hA[(q * 4 + 1) * 136 + colc] = (unsigned short)(hp01 >> 16);
    hA[(q * 4 + 2) * 136 + colc] = (unsigned short)(hp23 & 0xffffu);
    hA[(q * 4 + 3) * 136 + colc] = (unsigned short)(hp23 >> 16);
    ldsbar();
  }
}

extern "C" void kernel_launch(void* const* d_in, const int* in_sizes, int n_in,
                              void* d_out, int out_size, void* d_ws, size_t ws_size,
                              hipStream_t stream) {
  const float* X   = (const float*)d_in[0];
  const int*   seq = (const int*)  d_in[1];
  const float* Wg  = (const float*)d_in[2];
  const float* bg  = (const float*)d_in[3];
  const float* Wc  = (const float*)d_in[4];
  const float* bc  = (const float*)d_in[5];
  float* Y = (float*)d_out;
  (void)d_ws; (void)ws_size;

  hipLaunchKernelGGL(gru_fused, dim3(64), dim3(512), 0, stream,
                     X, seq, Wg, bg, Wc, bc, Y);
}

// Round 6
// 324.430 us; speedup vs baseline: 2.0656x; 2.0656x over previous
//
#include <hip/hip_runtime.h>

// Problem constants: B=1024, T=200, D=128, H=128
#define T_SZ 200
#define H_SZ 128

typedef __attribute__((ext_vector_type(8))) short    bf16x8;
typedef __attribute__((ext_vector_type(4))) float    f32x4;
typedef __attribute__((ext_vector_type(4))) int      i32x4;
typedef __attribute__((ext_vector_type(2))) unsigned u32x2;

__device__ __forceinline__ unsigned short f2bf(float f) {  // weight init only
  unsigned u = __builtin_bit_cast(unsigned, f);
  u += 0x7fffu + ((u >> 16) & 1u);
  return (unsigned short)(u >> 16);
}
// Single-instruction packed f32->bf16 (RNE, same rounding as f2bf).
__device__ __forceinline__ unsigned cvt_pk_bf16(float a, float b) {
  unsigned r;
  asm("v_cvt_pk_bf16_f32 %0, %1, %2" : "=v"(r) : "v"(a), "v"(b));
  return r;
}
__device__ __forceinline__ float sigmoid_fast(float x) {
  float e = __builtin_amdgcn_exp2f(-1.442695041f * x);
  return __builtin_amdgcn_rcpf(1.0f + e);
}
__device__ __forceinline__ float tanh_fast(float x) {
  float e = __builtin_amdgcn_exp2f(2.885390082f * x);
  return 1.0f - 2.0f * __builtin_amdgcn_rcpf(e + 1.0f);
}
// lgkmcnt(0)-only barrier: does NOT drain vmcnt (global stores / register
// prefetch loads stay in flight). 0xc07f = vmcnt(63) expcnt(7) lgkmcnt(0).
__device__ __forceinline__ void ldsbar() {
  __asm__ __volatile__("" ::: "memory");
  __builtin_amdgcn_s_waitcnt(0xc07f);
  __builtin_amdgcn_s_barrier();
  __asm__ __volatile__("" ::: "memory");
}

// ---------------------------------------------------------------------------
// Fused GRU, TRANSPOSED MFMA (C = W^T-frag x data-frag = [gatecol][batchrow]):
// lane (m16,q) holds batchrow m16, gate/cand cols q*4+i (+16w tile base).
// Wave w owns r cols [16w,+16), u cols [128+16w,+16), cand/h cols [16w,+16)
// — r,u,c,h are element-aligned in registers, so rh, u-blend, h-update are
// pure register ops AND the rh/h publishes are CONTIGUOUS ds_write_b64
// (A-layout [row=m16][k=col]), Y is one dwordx4/lane, slen one scalar/lane.
// The A-layout LDS reads (b128) and weight-fragment loads are unchanged:
// A-frag(row=m16,k) and B-frag(col=m16,k) read identical addresses.
// Phase structure:
//   P1(t): haf read -> r-MFMA(2+2, C-init = x-proj) -> sigmoid -> rh b64.
//   P2(t): rhf read; u-MFMA(4-chain, reg-only) fills shadow; cand-MFMA(2+2);
//          xproj(t+1) (12 MFMA, h-independent); activations; h b64 publish.
// x staged coalesced through LDS (dbuf + 2-reg global prefetch rotation).
// ---------------------------------------------------------------------------
__global__ __launch_bounds__(512, 1) void gru_fused(
    const float* __restrict__ X,    // [B,T,D]
    const int*   __restrict__ seq_len,
    const float* __restrict__ Wg,   // [256,256] rows 0..127 x-part, 128.. h-part
    const float* __restrict__ bg,   // [256]
    const float* __restrict__ Wc,   // [256,128] rows 0..127 x-part, 128.. rh-part
    const float* __restrict__ bc,   // [128]
    float* __restrict__ Y)          // [B,T,H]
{
  __shared__ unsigned short hA[16 * 136];      // h bf16, A-layout [row][k]
  __shared__ unsigned short rhA[16 * 136];     // r*h bf16, A-layout
  __shared__ unsigned short xA[2][16 * 136];   // x bf16, A-layout, dbuf

  const int tid  = threadIdx.x;
  const int lane = tid & 63;
  const int w    = tid >> 6;   // 0..7
  const int m16  = lane & 15;
  const int q    = lane >> 4;

  // ---- weight fragments (now MFMA A-operands; same addresses as before:
  // lane (m16,q) slot j = W[k = kb*32+q*8+j][col = tilebase+m16]) ----
  bf16x8 wgf[2][8];
  #pragma unroll
  for (int nt = 0; nt < 2; ++nt) {
    int col = nt * 128 + w * 16 + m16;
    #pragma unroll
    for (int kb = 0; kb < 8; ++kb) {
      bf16x8 f;
      #pragma unroll
      for (int j = 0; j < 8; ++j)
        f[j] = (short)f2bf(Wg[(size_t)(kb * 32 + q * 8 + j) * 256 + col]);
      wgf[nt][kb] = f;
    }
  }
  const int colc = w * 16 + m16;
  bf16x8 wcf[8];
  #pragma unroll
  for (int kb = 0; kb < 8; ++kb) {
    bf16x8 f;
    #pragma unroll
    for (int j = 0; j < 8; ++j)
      f[j] = (short)f2bf(Wc[(size_t)(kb * 32 + q * 8 + j) * 128 + colc]);
    wcf[kb] = f;
  }

  // ---- per-lane bias vectors (gate/cand cols q*4+i of this wave's tiles) ----
  const int col4 = w * 16 + q * 4;
  const f32x4 gbias_r = *(const f32x4*)&bg[col4];
  const f32x4 gbias_u = *(const f32x4*)&bg[128 + col4];
  const f32x4 cbias4  = *(const f32x4*)&bc[col4];

  const int bt = blockIdx.x;  // 0..63
  const int slen = seq_len[bt * 16 + m16];  // one batch row per lane

  float h[4] = {0.f, 0.f, 0.f, 0.f};  // h[m16][col4 + i]

  for (int idx = tid; idx < 16 * 136; idx += 512) hA[idx] = 0;

  // ---- x staging (coalesced): thread loads 4 floats of the 16x128 tile ----
  const int xrow = tid >> 5;        // 0..15
  const int xk4  = (tid & 31) * 4;  // k offset, 4 floats
  const float* xbase = X + (size_t)(bt * 16 + xrow) * T_SZ * 128 + xk4;

  auto xload = [&](int t, f32x4& r) {
    r = *(const f32x4*)(xbase + (size_t)t * 128);
  };
  auto xstage = [&](int buf, const f32x4& r) {
    unsigned d0 = cvt_pk_bf16(r.x, r.y);
    unsigned d1 = cvt_pk_bf16(r.z, r.w);
    *(u32x2*)&xA[buf][xrow * 136 + xk4] = (u32x2){d0, d1};
  };

  // Prologue: x(0),x(1) staged; x(2),x(3) in prefetch regs (2-reg rotation:
  // P1(t) stages x(t+2) from its reg, then reloads x(t+4) into it).
  f32x4 x0r, x1r, xrE, xrO;
  xload(0, x0r); xload(1, x1r);
  xstage(0, x0r); xstage(1, x1r);
  xload(2, xrE); xload(3, xrO);
  ldsbar();  // zero-init + xA[0],xA[1] visible

  // xproj(0): r/u/cand x-parts for the first step (become MFMA C-inits).
  f32x4 axrA, axuA, ccA, axrB, axuB, ccB;
  {
    bf16x8 xaf[4];
    #pragma unroll
    for (int kb = 0; kb < 4; ++kb)
      xaf[kb] = __builtin_bit_cast(bf16x8, *(const i32x4*)&xA[0][m16 * 136 + kb * 32 + q * 8]);
    f32x4 cc = cbias4, ar = gbias_r, au = gbias_u;
    #pragma unroll
    for (int kb = 0; kb < 4; ++kb) {
      cc = __builtin_amdgcn_mfma_f32_16x16x32_bf16(wcf[kb],    xaf[kb], cc, 0, 0, 0);
      ar = __builtin_amdgcn_mfma_f32_16x16x32_bf16(wgf[0][kb], xaf[kb], ar, 0, 0, 0);
      au = __builtin_amdgcn_mfma_f32_16x16x32_bf16(wgf[1][kb], xaf[kb], au, 0, 0, 0);
    }
    ccA = cc; axrA = ar; axuA = au;
  }
  ldsbar();  // prologue xA[0] readers drained before P1(0) overwrites it

  float* const ybase = Y + (size_t)(bt * 16 + m16) * T_SZ * H_SZ + col4;

  auto step = [&](int t, f32x4& xreg,
                  f32x4& axin_r, f32x4& axin_u, f32x4& ccin,
                  f32x4& axout_r, f32x4& axout_u, f32x4& ccout) {
    // ---- P1: r gate + rh publish ONLY (minimal pre-barrier path) ----
    bf16x8 haf[4];
    #pragma unroll
    for (int kb = 0; kb < 4; ++kb)
      haf[kb] = __builtin_bit_cast(bf16x8, *(const i32x4*)&hA[m16 * 136 + kb * 32 + q * 8]);

    // stage x(t+2) into xA[t&1] (readers drained at bar2(t-1)); reload reg
    if (t < 198) xstage(t & 1, xreg);
    if (t < 196) xload(t + 4, xreg);

    // r: two 2-deep MFMA chains, C-init carries bias + x-projection
    f32x4 ra = axin_r, rb = { 0.f, 0.f, 0.f, 0.f };
    ra = __builtin_amdgcn_mfma_f32_16x16x32_bf16(wgf[0][4], haf[0], ra, 0, 0, 0);
    ra = __builtin_amdgcn_mfma_f32_16x16x32_bf16(wgf[0][5], haf[1], ra, 0, 0, 0);
    rb = __builtin_amdgcn_mfma_f32_16x16x32_bf16(wgf[0][6], haf[2], rb, 0, 0, 0);
    rb = __builtin_amdgcn_mfma_f32_16x16x32_bf16(wgf[0][7], haf[3], rb, 0, 0, 0);

    // rh = sigmoid(r) * h — register op; publish as ONE contiguous b64
    float rh0 = sigmoid_fast(ra[0] + rb[0]) * h[0];
    float rh1 = sigmoid_fast(ra[1] + rb[1]) * h[1];
    float rh2 = sigmoid_fast(ra[2] + rb[2]) * h[2];
    float rh3 = sigmoid_fast(ra[3] + rb[3]) * h[3];
    *(u32x2*)&rhA[m16 * 136 + col4] =
        (u32x2){ cvt_pk_bf16(rh0, rh1), cvt_pk_bf16(rh2, rh3) };
    ldsbar();

    // ---- P2: u + candidate + xproj(t+1) + h update ----
    bf16x8 rhf[4];
    #pragma unroll
    for (int kb = 0; kb < 4; ++kb)
      rhf[kb] = __builtin_bit_cast(bf16x8, *(const i32x4*)&rhA[m16 * 136 + kb * 32 + q * 8]);
    bf16x8 xaf2[4];
    if (t < 199) {
      const unsigned short* xb = xA[(t + 1) & 1];
      #pragma unroll
      for (int kb = 0; kb < 4; ++kb)
        xaf2[kb] = __builtin_bit_cast(bf16x8, *(const i32x4*)&xb[m16 * 136 + kb * 32 + q * 8]);
    }

    // u: 4-deep chain, inputs all in registers — fills the rhf-read shadow.
    f32x4 ua = axin_u;
    ua = __builtin_amdgcn_mfma_f32_16x16x32_bf16(wgf[1][4], haf[0], ua, 0, 0, 0);
    ua = __builtin_amdgcn_mfma_f32_16x16x32_bf16(wgf[1][5], haf[1], ua, 0, 0, 0);
    ua = __builtin_amdgcn_mfma_f32_16x16x32_bf16(wgf[1][6], haf[2], ua, 0, 0, 0);
    ua = __builtin_amdgcn_mfma_f32_16x16x32_bf16(wgf[1][7], haf[3], ua, 0, 0, 0);

    // cand: 2+2 chains, C-init carries bias + x-projection
    f32x4 ca = ccin, cb = { 0.f, 0.f, 0.f, 0.f };
    ca = __builtin_amdgcn_mfma_f32_16x16x32_bf16(wcf[4], rhf[0], ca, 0, 0, 0);
    ca = __builtin_amdgcn_mfma_f32_16x16x32_bf16(wcf[5], rhf[1], ca, 0, 0, 0);
    cb = __builtin_amdgcn_mfma_f32_16x16x32_bf16(wcf[6], rhf[2], cb, 0, 0, 0);
    cb = __builtin_amdgcn_mfma_f32_16x16x32_bf16(wcf[7], rhf[3], cb, 0, 0, 0);

    if (t < 199) {  // xproj(t+1): h-independent filler
      f32x4 cc = cbias4, ar = gbias_r, au = gbias_u;
      #pragma unroll
      for (int kb = 0; kb < 4; ++kb) {
        cc = __builtin_amdgcn_mfma_f32_16x16x32_bf16(wcf[kb],    xaf2[kb], cc, 0, 0, 0);
        ar = __builtin_amdgcn_mfma_f32_16x16x32_bf16(wgf[0][kb], xaf2[kb], ar, 0, 0, 0);
        au = __builtin_amdgcn_mfma_f32_16x16x32_bf16(wgf[1][kb], xaf2[kb], au, 0, 0, 0);
      }
      ccout = cc; axout_r = ar; axout_u = au;
    }

    const bool valid = (t < slen);  // one scalar per lane
    f32x4 yv;
    #pragma unroll
    for (int i = 0; i < 4; ++i) {
      float u  = sigmoid_fast(ua[i]);
      float c  = tanh_fast(ca[i] + cb[i]);
      float hn = u * (h[i] - c) + c;   // u*h + (1-u)*c
      h[i]  = valid ? hn : h[i];
      yv[i] = valid ? hn : 0.0f;
    }
    *(f32x4*)(ybase + (size_t)t * H_SZ) = yv;   // one dwordx4 per lane
    *(u32x2*)&hA[m16 * 136 + col4] =
        (u32x2){ cvt_pk_bf16(h[0], h[1]), cvt_pk_bf16(h[2], h[3]) };
    ldsbar();
  };

  // 2-step unroll rotates the {axr,axu,cc} pipeline regs and x prefetch regs.
  for (int t = 0; t < 200; t += 2) {
    step(t,     xrE, axrA, axuA, ccA, axrB, axuB, ccB);
    step(t + 1, xrO, axrB, axuB, ccB, axrA, axuA, ccA);
  }
}

extern "C" void kernel_launch(void* const* d_in, const int* in_sizes, int n_in,
                              void* d_out, int out_size, void* d_ws, size_t ws_size,
                              hipStream_t stream) {
  const float* X   = (const float*)d_in[0];
  const int*   seq = (const int*)  d_in[1];
  const float* Wg  = (const float*)d_in[2];
  const float* bg  = (const float*)d_in[3];
  const float* Wc  = (const float*)d_in[4];
  const float* bc  = (const float*)d_in[5];
  float* Y = (float*)d_out;
  (void)d_ws; (void)ws_size;

  hipLaunchKernelGGL(gru_fused, dim3(64), dim3(512), 0, stream,
                     X, seq, Wg, bg, Wc, bc, Y);
}